// Round 14
// baseline (877.217 us; speedup 1.0000x reference)
//
#include <hip/hip_runtime.h>

#define T_STEPS 100
#define B_SZ    2048
#define IN_DIM  784
#define KPAD    800           // 25 x 32; pad multiplies zeros
#define HID_DIM 100
#define OUT_DIM 10
#define CSTR    100           // cur row stride (doubles)
#define BMR     64            // rows per block (wave = 16 rows)
#define CHUNK   160           // k per LDS-resident w chunk
#define NCHUNK  5
#define SPC     5             // 32-wide steps per chunk
#define KSTEPS  25            // global 32-wide steps
#define WROW    102           // w LDS row stride (floats); [160][102] = 65,280 B

typedef double f64x4 __attribute__((ext_vector_type(4)));
#define MFMA64(a, b, c) __builtin_amdgcn_mfma_f64_16x16x4f64((a), (b), (c), 0, 0, 0)

// ---------------- pad w1 to [100][800] (k 784..799 = 0) ----------------
__global__ void pad_w1(const float* __restrict__ w1, float* __restrict__ w1p) {
  int i = blockIdx.x * 256 + threadIdx.x;
  if (i >= HID_DIM * KPAD) return;
  int r = i / KPAD, k = i % KPAD;
  w1p[i] = (k < IN_DIM) ? w1[r * IN_DIM + k] : 0.0f;
}

// ---------------- Phase A: fp64 MFMA GEMM, chunk-resident w (10 barriers total) ----------------
// k-window remap (r10-proven): mfma #m uses k = 32S + 8*kg + m.
// x: per-lane contiguous 8-float runs, direct global->reg, 1-step prefetch.
// w: [160 k][100 rows] float in LDS, loaded once per chunk; 5 barrier-free steps per chunk.
// cols 0..95 on MFMA, cols 96..99 on the VALU pipe (r13-proven).
__global__ __launch_bounds__(256, 2)
void snn_gemm1(const float* __restrict__ x,     // [rows][784] (chunk-offset)
               const float* __restrict__ w1p,   // [100][800]
               double* __restrict__ cur)        // [rows][100]
{
  const int tid  = threadIdx.x;
  const int lane = tid & 63;
  const int wv   = tid >> 6;      // 0..3
  const int kg   = lane >> 4;     // 0..3 (k-slot label)
  const int il   = lane & 15;     // row/col label
  const int kg8  = kg * 8;
  const long rowBase = (long)blockIdx.x * BMR;

  __shared__ float wls[CHUNK][WROW];   // 65,280 B (single-buffered, chunk-resident)

  // ---- x: direct-from-global; lane (kg,il) row wv*16+il, 8 contiguous k per step ----
  const float* xrp = x + (rowBase + wv * 16 + il) * (long)IN_DIM;
  float xcur[8], xnxt[8];
  auto XLOAD = [&](int S, float* d) {
    if (S == KSTEPS - 1 && kg >= 2) {        // k >= 784 -> zeros (no OOB)
#pragma unroll
      for (int j = 0; j < 8; ++j) d[j] = 0.0f;
    } else {
      const float* p = xrp + S * 32 + kg8;
      *reinterpret_cast<float4*>(&d[0]) = *reinterpret_cast<const float4*>(p);
      *reinterpret_cast<float4*>(&d[4]) = *reinterpret_cast<const float4*>(p + 4);
    }
  };

  XLOAD(0, xcur);   // issue first x loads; probes run under their latency

  // ---- self-calibration: discover the true (lane,reg)->(row,col) D map ----
  f64x4 z = {0.0, 0.0, 0.0, 0.0};
  const double eil = (double)il;
  const double d0 = (kg == 0) ? 1.0 : 0.0;
  const double d1 = (kg == 1) ? 1.0 : 0.0;
  const double d2 = (kg == 2) ? 1.0 : 0.0;
  const double d3 = (kg == 3) ? 1.0 : 0.0;
  const f64x4 Prow0 = MFMA64(eil, d0, z);
  const f64x4 Prow1 = MFMA64(eil, d1, z);
  const f64x4 Pcol0 = MFMA64(d0, eil, z);
  const f64x4 Pcol1 = MFMA64(d1, eil, z);
  const f64x4 Pv0   = MFMA64(d0, d0, z);
  const f64x4 Pv1   = MFMA64(d1, d1, z);
  const f64x4 Pv2   = MFMA64(d2, d2, z);
  const f64x4 Pv3   = MFMA64(d3, d3, z);

  bool okl = true;
  int rowof[4], colof[4];
#pragma unroll
  for (int r = 0; r < 4; ++r) {
    okl = okl && (Pv0[r] == 1.0) && (Pv1[r] == 1.0) && (Pv2[r] == 1.0) && (Pv3[r] == 1.0);
    okl = okl && (Prow0[r] == Prow1[r]) && (Pcol0[r] == Pcol1[r]);
    const int rr = (int)Prow0[r];
    const int cc = (int)Pcol0[r];
    okl = okl && ((double)rr == Prow0[r]) && (rr >= 0) && (rr < 16);
    okl = okl && ((double)cc == Pcol0[r]) && (cc >= 0) && (cc < 16);
    rowof[r] = rr; colof[r] = cc;
  }
  if (__all(okl ? 1 : 0) == 0) {       // canonical fallback (not expected)
#pragma unroll
    for (int r = 0; r < 4; ++r) { rowof[r] = kg * 4 + r; colof[r] = il; }
  }

  f64x4 acc[6];
#pragma unroll
  for (int ht = 0; ht < 6; ++ht) acc[ht] = z;
  double acc4[4] = {0.0, 0.0, 0.0, 0.0};   // tail cols 96..99 (per-lane k-share)

#pragma unroll 1
  for (int c = 0; c < NCHUNK; ++c) {
    // ---- load w chunk [100 rows][160 k] -> wls[k][row]; 4000 float4 units ----
#pragma unroll 1
    for (int i = 0; i < 16; ++i) {
      const int idx = i * 256 + tid;
      if (idx < HID_DIM * (CHUNK / 4)) {
        const int r  = idx / (CHUNK / 4);
        const int kq = idx % (CHUNK / 4);
        const float4 wg = *reinterpret_cast<const float4*>(
            w1p + (long)r * KPAD + c * CHUNK + kq * 4);
        wls[kq * 4 + 0][r] = wg.x;
        wls[kq * 4 + 1][r] = wg.y;
        wls[kq * 4 + 2][r] = wg.z;
        wls[kq * 4 + 3][r] = wg.w;
      }
    }
    __syncthreads();

    // ---- 5 barrier-free KC32 steps against the resident chunk ----
#pragma unroll 1
    for (int ls = 0; ls < SPC; ++ls) {
      const int S = c * SPC + ls;
      if (S + 1 < KSTEPS) XLOAD(S + 1, xnxt);
      const int kb = ls * 32 + kg8;

#pragma unroll
      for (int m = 0; m < 8; ++m) {
        const double a0 = (double)xcur[m];
        double b[6];
#pragma unroll
        for (int ht = 0; ht < 6; ++ht)
          b[ht] = (double)wls[kb + m][ht * 16 + il];
#pragma unroll
        for (int ht = 0; ht < 6; ++ht)
          acc[ht] = MFMA64(a0, b[ht], acc[ht]);
        // tail cols 96..99 on the vector pipe (overlaps matrix pipe)
        const float4 wt = *reinterpret_cast<const float4*>(&wls[kb + m][96]);
        acc4[0] = fma(a0, (double)wt.x, acc4[0]);
        acc4[1] = fma(a0, (double)wt.y, acc4[1]);
        acc4[2] = fma(a0, (double)wt.z, acc4[2]);
        acc4[3] = fma(a0, (double)wt.w, acc4[3]);
      }
#pragma unroll
      for (int j = 0; j < 8; ++j) xcur[j] = xnxt[j];
    }
    __syncthreads();   // protect wls overwrite
  }

  // tail reduce across kg groups; order-free in fp64
#pragma unroll
  for (int cc2 = 0; cc2 < 4; ++cc2) {
    acc4[cc2] += __shfl_xor(acc4[cc2], 16);
    acc4[cc2] += __shfl_xor(acc4[cc2], 32);
  }

  // epilogue through the calibrated D map
  const long r0 = rowBase + wv * 16;
#pragma unroll
  for (int ht = 0; ht < 6; ++ht)
#pragma unroll
    for (int m = 0; m < 4; ++m)
      cur[(r0 + rowof[m]) * CSTR + ht * 16 + colof[m]] = acc[ht][m];
  if (kg == 0) {
    double* cp = cur + (r0 + il) * CSTR + 96;
    cp[0] = acc4[0]; cp[1] = acc4[1]; cp[2] = acc4[2]; cp[3] = acc4[3];
  }
}

// ---------------- Phase B: recursion, fp64 state; 2 timesteps per barrier pair (r13) ----------------
__global__ __launch_bounds__(256)
void snn_recur(const double* __restrict__ cur,  // [chunkT][2048][100]
               const float* __restrict__ w2,    // [10][100]
               double* __restrict__ mem1s, float* __restrict__ spk1s,  // [2048][100]
               double* __restrict__ mem2s, float* __restrict__ spk2s,  // [2048][10]
               float* __restrict__ outs,
               float* __restrict__ dout,
               int chunkT, int isFirst, int isLast)
{
  const int tid = threadIdx.x;
  const int b0  = blockIdx.x * 4;              // 4 samples per block
  __shared__ float w2l[OUT_DIM * HID_DIM];     // 1000
  __shared__ float spkl[2][4 * HID_DIM];       // two timesteps

  if (tid < 250)
    reinterpret_cast<float4*>(w2l)[tid] = reinterpret_cast<const float4*>(w2)[tid];

  const bool pa = tid < 100;                   // 4 samples * 100 / 4
  const int  sl = tid / 25, q4 = (tid % 25) * 4;
  const long aOff = (long)(b0 + sl) * HID_DIM + q4;
  double m1[4] = {0.0, 0.0, 0.0, 0.0};
  float4 s1 = make_float4(0.f, 0.f, 0.f, 0.f);
  if (pa && !isFirst) {
    const double2* mp = reinterpret_cast<const double2*>(mem1s + aOff);
    double2 a = mp[0], b = mp[1];
    m1[0] = a.x; m1[1] = a.y; m1[2] = b.x; m1[3] = b.y;
    s1 = *reinterpret_cast<const float4*>(spk1s + aOff);
  }

  const bool pb = tid < 80;                    // pair p=tid>>1 -> (sample,out); half=tid&1
  const int  pp = tid >> 1, hf = tid & 1;
  const int  ss = pp / 10, oo = pp % 10;
  const long bOff = (long)b0 * OUT_DIM + pp;
  double m2 = 0.0;
  float s2 = 0.f, oacc = 0.f;
  if (pb && !isFirst && hf == 0) { m2 = mem2s[bOff]; s2 = spk2s[bOff]; oacc = outs[bOff]; }

  __syncthreads();

  // prefetch cur for t=0 and t=1
  double2 ca0, cb0, ca1, cb1;
  if (pa) {
    const double2* cp0 = reinterpret_cast<const double2*>(cur + aOff);
    ca0 = cp0[0]; cb0 = cp0[1];
    const int t1 = (chunkT > 1) ? 1 : 0;
    const double2* cp1 = reinterpret_cast<const double2*>(
        cur + (long)t1 * B_SZ * HID_DIM + aOff);
    ca1 = cp1[0]; cb1 = cp1[1];
  }

  for (int tt = 0; tt < chunkT; tt += 2) {
    const bool two = (tt + 1 < chunkT);
    if (pa) {
      double cu0[4] = {ca0.x, ca0.y, cb0.x, cb0.y};
      double cu1[4] = {ca1.x, ca1.y, cb1.x, cb1.y};
      const int tn2 = (tt + 2 < chunkT) ? tt + 2 : chunkT - 1;
      const int tn3 = (tt + 3 < chunkT) ? tt + 3 : chunkT - 1;
      const double2* cp2 = reinterpret_cast<const double2*>(
          cur + (long)tn2 * B_SZ * HID_DIM + aOff);
      ca0 = cp2[0]; cb0 = cp2[1];
      const double2* cp3 = reinterpret_cast<const double2*>(
          cur + (long)tn3 * B_SZ * HID_DIM + aOff);
      ca1 = cp3[0]; cb1 = cp3[1];

      float4 sp0, sp1;
      float* sp0v = &sp0.x; float* sp1v = &sp1.x;
      const float* s1v = &s1.x;
#pragma unroll
      for (int j = 0; j < 4; ++j) {
        double m = 0.9 * m1[j];
        m = m + cu0[j];
        m = m - (double)s1v[j];
        sp0v[j] = (m > 1.0) ? 1.0f : 0.0f;
        m1[j] = m;
      }
      if (two) {
#pragma unroll
        for (int j = 0; j < 4; ++j) {
          double m = 0.9 * m1[j];
          m = m + cu1[j];
          m = m - (double)sp0v[j];
          sp1v[j] = (m > 1.0) ? 1.0f : 0.0f;
          m1[j] = m;
        }
        s1 = sp1;
      } else {
        s1 = sp0;
      }
      *reinterpret_cast<float4*>(&spkl[0][sl * HID_DIM + q4]) = sp0;
      if (two)
        *reinterpret_cast<float4*>(&spkl[1][sl * HID_DIM + q4]) = sp1;
    }
    __syncthreads();
    if (pb) {
      const float* wr = &w2l[oo * HID_DIM] + hf * 50;
#pragma unroll 1
      for (int u = 0; u < 2; ++u) {
        if (u == 1 && !two) break;
        const float* sr = &spkl[u][ss * HID_DIM] + hf * 50;
        double a0 = 0.0, a1 = 0.0;
#pragma unroll
        for (int h = 0; h < 50; h += 2) {      // order-free in fp64
          a0 = fma((double)sr[h],     (double)wr[h],     a0);
          a1 = fma((double)sr[h + 1], (double)wr[h + 1], a1);
        }
        double a = a0 + a1;
        a = a + __shfl_xor(a, 1);              // combine halves
        if (hf == 0) {
          double m = 0.9 * m2;
          m = m + a;
          m = m - (double)s2;
          const float sp = (m > 1.0) ? 1.0f : 0.0f;
          m2 = m; s2 = sp; oacc += sp;
        }
      }
    }
    __syncthreads();
  }

  if (pa) {
    double2* mp = reinterpret_cast<double2*>(mem1s + aOff);
    mp[0] = make_double2(m1[0], m1[1]);
    mp[1] = make_double2(m1[2], m1[3]);
    *reinterpret_cast<float4*>(spk1s + aOff) = s1;
  }
  if (pb && hf == 0) {
    mem2s[bOff] = m2; spk2s[bOff] = s2; outs[bOff] = oacc;
    if (isLast) dout[bOff] = oacc;
  }
}

// ---------------- host ----------------
extern "C" void kernel_launch(void* const* d_in, const int* in_sizes, int n_in,
                              void* d_out, int out_size, void* d_ws, size_t ws_size,
                              hipStream_t stream) {
  const float* x  = (const float*)d_in[0];   // [100,2048,784]
  const float* w1 = (const float*)d_in[1];   // [100,784]
  const float* w2 = (const float*)d_in[2];   // [10,100]
  float* out = (float*)d_out;

  char* ws = (char*)d_ws;
  // byte offsets: w1p(f,[100][800]) 320,000 | mem1(d) 1,638,400 | spk1(f) 819,200 |
  //               mem2(d) 163,840 | spk2(f) 81,920 | outacc(f) 81,920 | cur(d, stride 100)...
  float*  w1p   = (float*) (ws);
  double* mem1s = (double*)(ws +  320000);
  float*  spk1s = (float*) (ws + 1958400);
  double* mem2s = (double*)(ws + 2777600);
  float*  spk2s = (float*) (ws + 2941440);
  float*  outs  = (float*) (ws + 3023360);
  double* cur   = (double*)(ws + 3105280);

  pad_w1<<<dim3((HID_DIM * KPAD + 255) / 256), dim3(256), 0, stream>>>(w1, w1p);

  const size_t perT = (size_t)B_SZ * HID_DIM * 8;  // 1,638,400 B of cur per timestep
  size_t curCap = ws_size > (size_t)3105280 ? ws_size - 3105280 : 0;
  int Tc = (int)(curCap / perT);
  if (Tc > T_STEPS) Tc = T_STEPS;
  if (Tc < 1) Tc = 1;

  for (int t0 = 0; t0 < T_STEPS; t0 += Tc) {
    const int ct = (T_STEPS - t0 < Tc) ? (T_STEPS - t0) : Tc;
    snn_gemm1<<<dim3(ct * (B_SZ / BMR)), dim3(256), 0, stream>>>(
        x + (size_t)t0 * B_SZ * IN_DIM, w1p, cur);
    snn_recur<<<dim3(B_SZ / 4), dim3(256), 0, stream>>>(
        cur, w2, mem1s, spk1s, mem2s, spk2s, outs, out,
        ct, (t0 == 0) ? 1 : 0, (t0 + ct >= T_STEPS) ? 1 : 0);
  }
}

// Round 15
// 714.917 us; speedup vs baseline: 1.2270x; 1.2270x over previous
//
#include <hip/hip_runtime.h>

#define T_STEPS 100
#define B_SZ    2048
#define IN_DIM  784
#define KPAD    800           // 25 x 32; pad region is zeros
#define HID_DIM 100
#define OUT_DIM 10
#define CSTR    100           // cur row stride (doubles)
#define BMR     64            // rows per block (wave = 16 rows)
#define KC      32
#define KSTEPS  25            // KPAD / KC
#define WLP     114           // w LDS k-stride: stores 2-way; remapped reads 2-way (8*114%32==16)

typedef double f64x4 __attribute__((ext_vector_type(4)));
#define MFMA64(a, b, c) __builtin_amdgcn_mfma_f64_16x16x4f64((a), (b), (c), 0, 0, 0)

// ---------------- pad w1 to [100][800] (k 784..799 = 0) ----------------
__global__ void pad_w1(const float* __restrict__ w1, float* __restrict__ w1p) {
  int i = blockIdx.x * 256 + threadIdx.x;
  if (i >= HID_DIM * KPAD) return;
  int r = i / KPAD, k = i % KPAD;
  w1p[i] = (k < IN_DIM) ? w1[r * IN_DIM + k] : 0.0f;
}

// ---------------- Phase A: fp64 MFMA GEMM ----------------
// k-window remap (r10-proven): mfma #m uses k = 32S + 8*kg + m.
// x: per-lane contiguous 8-float runs direct global->reg, 1-step prefetch (NO x LDS).
// w: double-buffered LDS [2][32][114] streamed per KC32 step (r13 convoy, half the barriers).
// cols 0..95 on MFMA, cols 96..99 on the VALU pipe (r13-proven).
__global__ __launch_bounds__(256, 4)
void snn_gemm1(const float* __restrict__ x,     // [rows][784] (chunk-offset)
               const float* __restrict__ w1p,   // [100][800]
               double* __restrict__ cur)        // [rows][100]
{
  const int tid  = threadIdx.x;
  const int lane = tid & 63;
  const int wv   = tid >> 6;      // 0..3
  const int kg   = lane >> 4;     // 0..3 (k-slot label)
  const int il   = lane & 15;     // row/col label
  const int kg8  = kg * 8;
  const long rowBase = (long)blockIdx.x * BMR;

  __shared__ float wls[2][KC][WLP];   // 29,184 B

  // ---- w staging: 200 threads; thread: row=t>>1, k-half=(t&1)*16 (4 float4) ----
  const int  wrow = tid >> 1;
  const int  skh  = (tid & 1) * 16;
  const bool dow  = tid < 2 * HID_DIM;
  const float* wsrc = w1p + (long)wrow * KPAD + skh;
  float4 wg0, wg1, wg2, wg3;

  auto WLOAD = [&](int s) {
    if (dow) {
      const float4* wp = reinterpret_cast<const float4*>(wsrc + s * KC);
      wg0 = wp[0]; wg1 = wp[1]; wg2 = wp[2]; wg3 = wp[3];
    }
  };
  auto WSTORE = [&](int buf) {
    if (dow) {
      float* b0 = &wls[buf][skh][wrow];
      b0[0 * WLP]  = wg0.x; b0[1 * WLP]  = wg0.y; b0[2 * WLP]  = wg0.z; b0[3 * WLP]  = wg0.w;
      b0[4 * WLP]  = wg1.x; b0[5 * WLP]  = wg1.y; b0[6 * WLP]  = wg1.z; b0[7 * WLP]  = wg1.w;
      b0[8 * WLP]  = wg2.x; b0[9 * WLP]  = wg2.y; b0[10 * WLP] = wg2.z; b0[11 * WLP] = wg2.w;
      b0[12 * WLP] = wg3.x; b0[13 * WLP] = wg3.y; b0[14 * WLP] = wg3.z; b0[15 * WLP] = wg3.w;
    }
  };

  // ---- x: direct-from-global; lane (kg,il) row wv*16+il, 8 contiguous k per step ----
  const float* xrp = x + (rowBase + wv * 16 + il) * (long)IN_DIM;
  float xcur[8], xnxt[8];
  auto XLOAD = [&](int S, float* d) {
    if (S == KSTEPS - 1 && kg >= 2) {        // k >= 784 -> zeros (no OOB)
#pragma unroll
      for (int j = 0; j < 8; ++j) d[j] = 0.0f;
    } else {
      const float* p = xrp + S * KC + kg8;
      *reinterpret_cast<float4*>(&d[0]) = *reinterpret_cast<const float4*>(p);
      *reinterpret_cast<float4*>(&d[4]) = *reinterpret_cast<const float4*>(p + 4);
    }
  };

  // issue first global loads; probes run under their latency
  WLOAD(0); XLOAD(0, xcur);

  // ---- self-calibration: discover the true (lane,reg)->(row,col) D map ----
  f64x4 z = {0.0, 0.0, 0.0, 0.0};
  const double eil = (double)il;
  const double d0 = (kg == 0) ? 1.0 : 0.0;
  const double d1 = (kg == 1) ? 1.0 : 0.0;
  const double d2 = (kg == 2) ? 1.0 : 0.0;
  const double d3 = (kg == 3) ? 1.0 : 0.0;
  const f64x4 Prow0 = MFMA64(eil, d0, z);
  const f64x4 Prow1 = MFMA64(eil, d1, z);
  const f64x4 Pcol0 = MFMA64(d0, eil, z);
  const f64x4 Pcol1 = MFMA64(d1, eil, z);
  const f64x4 Pv0   = MFMA64(d0, d0, z);
  const f64x4 Pv1   = MFMA64(d1, d1, z);
  const f64x4 Pv2   = MFMA64(d2, d2, z);
  const f64x4 Pv3   = MFMA64(d3, d3, z);

  bool okl = true;
  int rowof[4], colof[4];
#pragma unroll
  for (int r = 0; r < 4; ++r) {
    okl = okl && (Pv0[r] == 1.0) && (Pv1[r] == 1.0) && (Pv2[r] == 1.0) && (Pv3[r] == 1.0);
    okl = okl && (Prow0[r] == Prow1[r]) && (Pcol0[r] == Pcol1[r]);
    const int rr = (int)Prow0[r];
    const int cc = (int)Pcol0[r];
    okl = okl && ((double)rr == Prow0[r]) && (rr >= 0) && (rr < 16);
    okl = okl && ((double)cc == Pcol0[r]) && (cc >= 0) && (cc < 16);
    rowof[r] = rr; colof[r] = cc;
  }
  if (__all(okl ? 1 : 0) == 0) {       // canonical fallback (not expected)
#pragma unroll
    for (int r = 0; r < 4; ++r) { rowof[r] = kg * 4 + r; colof[r] = il; }
  }

  f64x4 acc[6];
#pragma unroll
  for (int ht = 0; ht < 6; ++ht) acc[ht] = z;
  double acc4[4] = {0.0, 0.0, 0.0, 0.0};   // tail cols 96..99 (per-lane k-share)

  WSTORE(0); WLOAD(1);
  __syncthreads();

#pragma unroll 1
  for (int s = 0; s < KSTEPS; ++s) {
    const int buf = s & 1;
    if (s + 1 < KSTEPS) { WSTORE(buf ^ 1); XLOAD(s + 1, xnxt); }
    if (s + 2 < KSTEPS) WLOAD(s + 2);

#pragma unroll
    for (int m = 0; m < 8; ++m) {
      const double a0 = (double)xcur[m];
      const int kr = kg8 + m;
      double b[6];
#pragma unroll
      for (int ht = 0; ht < 6; ++ht)
        b[ht] = (double)wls[buf][kr][ht * 16 + il];
#pragma unroll
      for (int ht = 0; ht < 6; ++ht)
        acc[ht] = MFMA64(a0, b[ht], acc[ht]);
      // tail cols 96..99 on the vector pipe (overlaps matrix pipe)
      const float4 wt = *reinterpret_cast<const float4*>(&wls[buf][kr][96]);
      acc4[0] = fma(a0, (double)wt.x, acc4[0]);
      acc4[1] = fma(a0, (double)wt.y, acc4[1]);
      acc4[2] = fma(a0, (double)wt.z, acc4[2]);
      acc4[3] = fma(a0, (double)wt.w, acc4[3]);
    }
    __syncthreads();
#pragma unroll
    for (int j = 0; j < 8; ++j) xcur[j] = xnxt[j];
  }

  // tail reduce across kg groups; order-free in fp64
#pragma unroll
  for (int c = 0; c < 4; ++c) {
    acc4[c] += __shfl_xor(acc4[c], 16);
    acc4[c] += __shfl_xor(acc4[c], 32);
  }

  // epilogue through the calibrated D map
  const long r0 = rowBase + wv * 16;
#pragma unroll
  for (int ht = 0; ht < 6; ++ht)
#pragma unroll
    for (int m = 0; m < 4; ++m)
      cur[(r0 + rowof[m]) * CSTR + ht * 16 + colof[m]] = acc[ht][m];
  if (kg == 0) {
    double* cp = cur + (r0 + il) * CSTR + 96;
    cp[0] = acc4[0]; cp[1] = acc4[1]; cp[2] = acc4[2]; cp[3] = acc4[3];
  }
}

// ---------------- Phase B: recursion, fp64 state; 2 timesteps per barrier pair (r13) ----------------
__global__ __launch_bounds__(256)
void snn_recur(const double* __restrict__ cur,  // [chunkT][2048][100]
               const float* __restrict__ w2,    // [10][100]
               double* __restrict__ mem1s, float* __restrict__ spk1s,  // [2048][100]
               double* __restrict__ mem2s, float* __restrict__ spk2s,  // [2048][10]
               float* __restrict__ outs,
               float* __restrict__ dout,
               int chunkT, int isFirst, int isLast)
{
  const int tid = threadIdx.x;
  const int b0  = blockIdx.x * 4;              // 4 samples per block
  __shared__ float w2l[OUT_DIM * HID_DIM];     // 1000
  __shared__ float spkl[2][4 * HID_DIM];       // two timesteps

  if (tid < 250)
    reinterpret_cast<float4*>(w2l)[tid] = reinterpret_cast<const float4*>(w2)[tid];

  const bool pa = tid < 100;                   // 4 samples * 100 / 4
  const int  sl = tid / 25, q4 = (tid % 25) * 4;
  const long aOff = (long)(b0 + sl) * HID_DIM + q4;
  double m1[4] = {0.0, 0.0, 0.0, 0.0};
  float4 s1 = make_float4(0.f, 0.f, 0.f, 0.f);
  if (pa && !isFirst) {
    const double2* mp = reinterpret_cast<const double2*>(mem1s + aOff);
    double2 a = mp[0], b = mp[1];
    m1[0] = a.x; m1[1] = a.y; m1[2] = b.x; m1[3] = b.y;
    s1 = *reinterpret_cast<const float4*>(spk1s + aOff);
  }

  const bool pb = tid < 80;                    // pair p=tid>>1 -> (sample,out); half=tid&1
  const int  pp = tid >> 1, hf = tid & 1;
  const int  ss = pp / 10, oo = pp % 10;
  const long bOff = (long)b0 * OUT_DIM + pp;
  double m2 = 0.0;
  float s2 = 0.f, oacc = 0.f;
  if (pb && !isFirst && hf == 0) { m2 = mem2s[bOff]; s2 = spk2s[bOff]; oacc = outs[bOff]; }

  __syncthreads();

  // prefetch cur for t=0 and t=1
  double2 ca0, cb0, ca1, cb1;
  if (pa) {
    const double2* cp0 = reinterpret_cast<const double2*>(cur + aOff);
    ca0 = cp0[0]; cb0 = cp0[1];
    const int t1 = (chunkT > 1) ? 1 : 0;
    const double2* cp1 = reinterpret_cast<const double2*>(
        cur + (long)t1 * B_SZ * HID_DIM + aOff);
    ca1 = cp1[0]; cb1 = cp1[1];
  }

  for (int tt = 0; tt < chunkT; tt += 2) {
    const bool two = (tt + 1 < chunkT);
    if (pa) {
      double cu0[4] = {ca0.x, ca0.y, cb0.x, cb0.y};
      double cu1[4] = {ca1.x, ca1.y, cb1.x, cb1.y};
      const int tn2 = (tt + 2 < chunkT) ? tt + 2 : chunkT - 1;
      const int tn3 = (tt + 3 < chunkT) ? tt + 3 : chunkT - 1;
      const double2* cp2 = reinterpret_cast<const double2*>(
          cur + (long)tn2 * B_SZ * HID_DIM + aOff);
      ca0 = cp2[0]; cb0 = cp2[1];
      const double2* cp3 = reinterpret_cast<const double2*>(
          cur + (long)tn3 * B_SZ * HID_DIM + aOff);
      ca1 = cp3[0]; cb1 = cp3[1];

      float4 sp0, sp1;
      float* sp0v = &sp0.x; float* sp1v = &sp1.x;
      const float* s1v = &s1.x;
#pragma unroll
      for (int j = 0; j < 4; ++j) {
        double m = 0.9 * m1[j];
        m = m + cu0[j];
        m = m - (double)s1v[j];
        sp0v[j] = (m > 1.0) ? 1.0f : 0.0f;
        m1[j] = m;
      }
      if (two) {
#pragma unroll
        for (int j = 0; j < 4; ++j) {
          double m = 0.9 * m1[j];
          m = m + cu1[j];
          m = m - (double)sp0v[j];
          sp1v[j] = (m > 1.0) ? 1.0f : 0.0f;
          m1[j] = m;
        }
        s1 = sp1;
      } else {
        s1 = sp0;
      }
      *reinterpret_cast<float4*>(&spkl[0][sl * HID_DIM + q4]) = sp0;
      if (two)
        *reinterpret_cast<float4*>(&spkl[1][sl * HID_DIM + q4]) = sp1;
    }
    __syncthreads();
    if (pb) {
      const float* wr = &w2l[oo * HID_DIM] + hf * 50;
#pragma unroll 1
      for (int u = 0; u < 2; ++u) {
        if (u == 1 && !two) break;
        const float* sr = &spkl[u][ss * HID_DIM] + hf * 50;
        double a0 = 0.0, a1 = 0.0;
#pragma unroll
        for (int h = 0; h < 50; h += 2) {      // order-free in fp64
          a0 = fma((double)sr[h],     (double)wr[h],     a0);
          a1 = fma((double)sr[h + 1], (double)wr[h + 1], a1);
        }
        double a = a0 + a1;
        a = a + __shfl_xor(a, 1);              // combine halves
        if (hf == 0) {
          double m = 0.9 * m2;
          m = m + a;
          m = m - (double)s2;
          const float sp = (m > 1.0) ? 1.0f : 0.0f;
          m2 = m; s2 = sp; oacc += sp;
        }
      }
    }
    __syncthreads();
  }

  if (pa) {
    double2* mp = reinterpret_cast<double2*>(mem1s + aOff);
    mp[0] = make_double2(m1[0], m1[1]);
    mp[1] = make_double2(m1[2], m1[3]);
    *reinterpret_cast<float4*>(spk1s + aOff) = s1;
  }
  if (pb && hf == 0) {
    mem2s[bOff] = m2; spk2s[bOff] = s2; outs[bOff] = oacc;
    if (isLast) dout[bOff] = oacc;
  }
}

// ---------------- host ----------------
extern "C" void kernel_launch(void* const* d_in, const int* in_sizes, int n_in,
                              void* d_out, int out_size, void* d_ws, size_t ws_size,
                              hipStream_t stream) {
  const float* x  = (const float*)d_in[0];   // [100,2048,784]
  const float* w1 = (const float*)d_in[1];   // [100,784]
  const float* w2 = (const float*)d_in[2];   // [10,100]
  float* out = (float*)d_out;

  char* ws = (char*)d_ws;
  // byte offsets: w1p(f,[100][800]) 320,000 | mem1(d) 1,638,400 | spk1(f) 819,200 |
  //               mem2(d) 163,840 | spk2(f) 81,920 | outacc(f) 81,920 | cur(d, stride 100)...
  float*  w1p   = (float*) (ws);
  double* mem1s = (double*)(ws +  320000);
  float*  spk1s = (float*) (ws + 1958400);
  double* mem2s = (double*)(ws + 2777600);
  float*  spk2s = (float*) (ws + 2941440);
  float*  outs  = (float*) (ws + 3023360);
  double* cur   = (double*)(ws + 3105280);

  pad_w1<<<dim3((HID_DIM * KPAD + 255) / 256), dim3(256), 0, stream>>>(w1, w1p);

  const size_t perT = (size_t)B_SZ * HID_DIM * 8;  // 1,638,400 B of cur per timestep
  size_t curCap = ws_size > (size_t)3105280 ? ws_size - 3105280 : 0;
  int Tc = (int)(curCap / perT);
  if (Tc > T_STEPS) Tc = T_STEPS;
  if (Tc < 1) Tc = 1;

  for (int t0 = 0; t0 < T_STEPS; t0 += Tc) {
    const int ct = (T_STEPS - t0 < Tc) ? (T_STEPS - t0) : Tc;
    snn_gemm1<<<dim3(ct * (B_SZ / BMR)), dim3(256), 0, stream>>>(
        x + (size_t)t0 * B_SZ * IN_DIM, w1p, cur);
    snn_recur<<<dim3(B_SZ / 4), dim3(256), 0, stream>>>(
        cur, w2, mem1s, spk1s, mem2s, spk2s, outs, out,
        ct, (t0 == 0) ? 1 : 0, (t0 + ct >= T_STEPS) ? 1 : 0);
  }
}

// Round 16
// 675.728 us; speedup vs baseline: 1.2982x; 1.0580x over previous
//
#include <hip/hip_runtime.h>

#define T_STEPS 100
#define B_SZ    2048
#define IN_DIM  784
#define HID_DIM 100
#define OUT_DIM 10
#define CSTR    100           // cur row stride (doubles) — no padding
#define BMR     64            // rows per block (wave = 16 rows)
#define KC      16
#define NSTEP   (IN_DIM / KC) // 49
#define XLP     84            // x LDS k-stride (r9-proven)
#define WLP     112           // w LDS k-stride: kg offsets 0/16 mod 32 -> 2-way (free)

typedef double f64x4 __attribute__((ext_vector_type(4)));
#define MFMA64(a, b, c) __builtin_amdgcn_mfma_f64_16x16x4f64((a), (b), (c), 0, 0, 0)

// ---------------- Phase A: fp64 MFMA GEMM (cols 0..95) + VALU fp64 tail (cols 96..99) ----------------
// r13-proven optimum (615us GEMM, MfmaUtil 70%): x+w double-buffered LDS, 1 barrier/chunk,
// 6 MFMA col-tiles + tail cols on the VALU pipe.
__global__ __launch_bounds__(256, 4)
void snn_gemm1(const float* __restrict__ x,     // [rows][784] (chunk-offset)
               const float* __restrict__ w1,    // [100][784] (unpadded)
               double* __restrict__ cur)        // [rows][100]
{
  const int tid  = threadIdx.x;
  const int lane = tid & 63;
  const int wv   = tid >> 6;      // 0..3
  const int kg   = lane >> 4;     // 0..3 (k-slot label)
  const int il   = lane & 15;     // row/col label
  const long rowBase = (long)blockIdx.x * BMR;

  __shared__ float xls[2][KC][XLP];   // 10752 B
  __shared__ float wls[2][KC][WLP];   // 14336 B (rows 0..99 used)

  // x stage: thread t: row=t>>2, kq=(t&3)*4
  const int xrow = tid >> 2;
  const int xq   = (tid & 3) * 4;
  const float* xsrc = x + (rowBase + xrow) * (long)IN_DIM + xq;
  // w stage: t<200: row=t>>1 (0..99), k-half=(t&1)*8
  const int  wrow = tid >> 1;
  const int  skh  = (tid & 1) * 8;
  const float* wsrc = w1 + (long)wrow * IN_DIM + skh;
  const bool   dow  = tid < 2 * HID_DIM;   // 200 threads stage w

  float4 xg, wa, wb;
  auto LOAD = [&](int s) {
    xg = *reinterpret_cast<const float4*>(xsrc + s * KC);
    if (dow) {
      const float4* wp = reinterpret_cast<const float4*>(wsrc + s * KC);
      wa = wp[0]; wb = wp[1];
    }
  };
  auto STORE = [&](int buf) {
    xls[buf][xq + 0][xrow] = xg.x; xls[buf][xq + 1][xrow] = xg.y;
    xls[buf][xq + 2][xrow] = xg.z; xls[buf][xq + 3][xrow] = xg.w;
    if (dow) {
      wls[buf][skh + 0][wrow] = wa.x; wls[buf][skh + 1][wrow] = wa.y;
      wls[buf][skh + 2][wrow] = wa.z; wls[buf][skh + 3][wrow] = wa.w;
      wls[buf][skh + 4][wrow] = wb.x; wls[buf][skh + 5][wrow] = wb.y;
      wls[buf][skh + 6][wrow] = wb.z; wls[buf][skh + 7][wrow] = wb.w;
    }
  };

  // issue first global loads; run calibration probes under their latency
  LOAD(0);

  // ---- self-calibration: discover the true (lane,reg)->(row,col) D map ----
  f64x4 z = {0.0, 0.0, 0.0, 0.0};
  const double eil = (double)il;
  const double d0 = (kg == 0) ? 1.0 : 0.0;
  const double d1 = (kg == 1) ? 1.0 : 0.0;
  const double d2 = (kg == 2) ? 1.0 : 0.0;
  const double d3 = (kg == 3) ? 1.0 : 0.0;
  const f64x4 Prow0 = MFMA64(eil, d0, z);
  const f64x4 Prow1 = MFMA64(eil, d1, z);
  const f64x4 Pcol0 = MFMA64(d0, eil, z);
  const f64x4 Pcol1 = MFMA64(d1, eil, z);
  const f64x4 Pv0   = MFMA64(d0, d0, z);
  const f64x4 Pv1   = MFMA64(d1, d1, z);
  const f64x4 Pv2   = MFMA64(d2, d2, z);
  const f64x4 Pv3   = MFMA64(d3, d3, z);

  bool okl = true;
  int rowof[4], colof[4];
#pragma unroll
  for (int r = 0; r < 4; ++r) {
    okl = okl && (Pv0[r] == 1.0) && (Pv1[r] == 1.0) && (Pv2[r] == 1.0) && (Pv3[r] == 1.0);
    okl = okl && (Prow0[r] == Prow1[r]) && (Pcol0[r] == Pcol1[r]);
    const int rr = (int)Prow0[r];
    const int cc = (int)Pcol0[r];
    okl = okl && ((double)rr == Prow0[r]) && (rr >= 0) && (rr < 16);
    okl = okl && ((double)cc == Pcol0[r]) && (cc >= 0) && (cc < 16);
    rowof[r] = rr; colof[r] = cc;
  }
  if (__all(okl ? 1 : 0) == 0) {       // canonical fallback (not expected)
#pragma unroll
    for (int r = 0; r < 4; ++r) { rowof[r] = kg * 4 + r; colof[r] = il; }
  }

  f64x4 acc[6];
#pragma unroll
  for (int ht = 0; ht < 6; ++ht) acc[ht] = z;
  double acc4[4] = {0.0, 0.0, 0.0, 0.0};   // tail cols 96..99, partial over kg's k share

  STORE(0); LOAD(1);
  __syncthreads();

#pragma unroll 1
  for (int s = 0; s < NSTEP; ++s) {
    if (s + 1 < NSTEP) STORE((s + 1) & 1);
    if (s + 2 < NSTEP) LOAD(s + 2);
    const int buf = s & 1;

#pragma unroll
    for (int kk = 0; kk < 4; ++kk) {
      const int kr = kk * 4 + kg;
      const double a0 = (double)xls[buf][kr][wv * 16 + il];
      double b[6];
#pragma unroll
      for (int ht = 0; ht < 6; ++ht)
        b[ht] = (double)wls[buf][kr][ht * 16 + il];
#pragma unroll
      for (int ht = 0; ht < 6; ++ht)
        acc[ht] = MFMA64(a0, b[ht], acc[ht]);
      // tail: cols 96..99 on the vector pipe (overlaps the matrix pipe)
      const float4 wt = *reinterpret_cast<const float4*>(&wls[buf][kr][96]);
      acc4[0] = fma(a0, (double)wt.x, acc4[0]);
      acc4[1] = fma(a0, (double)wt.y, acc4[1]);
      acc4[2] = fma(a0, (double)wt.z, acc4[2]);
      acc4[3] = fma(a0, (double)wt.w, acc4[3]);
    }
    __syncthreads();
  }

  // tail reduce across kg groups (lanes il, il+16, il+32, il+48); order-free in fp64
#pragma unroll
  for (int c = 0; c < 4; ++c) {
    acc4[c] += __shfl_xor(acc4[c], 16);
    acc4[c] += __shfl_xor(acc4[c], 32);
  }

  // epilogue: MFMA tiles through the calibrated D map
  const long r0 = rowBase + wv * 16;
#pragma unroll
  for (int ht = 0; ht < 6; ++ht)
#pragma unroll
    for (int m = 0; m < 4; ++m)
      cur[(r0 + rowof[m]) * CSTR + ht * 16 + colof[m]] = acc[ht][m];
  // epilogue: tail cols
  if (kg == 0) {
    double* cp = cur + (r0 + il) * CSTR + 96;
    cp[0] = acc4[0]; cp[1] = acc4[1]; cp[2] = acc4[2]; cp[3] = acc4[3];
  }
}

// ---------------- Phase B: recursion, fp64 state; 2 timesteps per barrier pair ----------------
__global__ __launch_bounds__(256)
void snn_recur(const double* __restrict__ cur,  // [chunkT][2048][100]
               const float* __restrict__ w2,    // [10][100]
               double* __restrict__ mem1s, float* __restrict__ spk1s,  // [2048][100]
               double* __restrict__ mem2s, float* __restrict__ spk2s,  // [2048][10]
               float* __restrict__ outs,
               float* __restrict__ dout,
               int chunkT, int isFirst, int isLast)
{
  const int tid = threadIdx.x;
  const int b0  = blockIdx.x * 4;              // 4 samples per block
  __shared__ float w2l[OUT_DIM * HID_DIM];     // 1000
  __shared__ float spkl[2][4 * HID_DIM];       // two timesteps

  if (tid < 250)
    reinterpret_cast<float4*>(w2l)[tid] = reinterpret_cast<const float4*>(w2)[tid];

  const bool pa = tid < 100;                   // 4 samples * 100 / 4
  const int  sl = tid / 25, q4 = (tid % 25) * 4;
  const long aOff = (long)(b0 + sl) * HID_DIM + q4;
  double m1[4] = {0.0, 0.0, 0.0, 0.0};
  float4 s1 = make_float4(0.f, 0.f, 0.f, 0.f);
  if (pa && !isFirst) {
    const double2* mp = reinterpret_cast<const double2*>(mem1s + aOff);
    double2 a = mp[0], b = mp[1];
    m1[0] = a.x; m1[1] = a.y; m1[2] = b.x; m1[3] = b.y;
    s1 = *reinterpret_cast<const float4*>(spk1s + aOff);
  }

  const bool pb = tid < 80;                    // pair p=tid>>1 -> (sample,out); half=tid&1
  const int  pp = tid >> 1, hf = tid & 1;
  const int  ss = pp / 10, oo = pp % 10;
  const long bOff = (long)b0 * OUT_DIM + pp;
  double m2 = 0.0;
  float s2 = 0.f, oacc = 0.f;
  if (pb && !isFirst && hf == 0) { m2 = mem2s[bOff]; s2 = spk2s[bOff]; oacc = outs[bOff]; }

  __syncthreads();

  // prefetch cur for t=0 and t=1
  double2 ca0, cb0, ca1, cb1;
  if (pa) {
    const double2* cp0 = reinterpret_cast<const double2*>(cur + aOff);
    ca0 = cp0[0]; cb0 = cp0[1];
    const int t1 = (chunkT > 1) ? 1 : 0;
    const double2* cp1 = reinterpret_cast<const double2*>(
        cur + (long)t1 * B_SZ * HID_DIM + aOff);
    ca1 = cp1[0]; cb1 = cp1[1];
  }

  for (int tt = 0; tt < chunkT; tt += 2) {
    const bool two = (tt + 1 < chunkT);
    if (pa) {
      double cu0[4] = {ca0.x, ca0.y, cb0.x, cb0.y};
      double cu1[4] = {ca1.x, ca1.y, cb1.x, cb1.y};
      // prefetch tt+2 / tt+3
      const int tn2 = (tt + 2 < chunkT) ? tt + 2 : chunkT - 1;
      const int tn3 = (tt + 3 < chunkT) ? tt + 3 : chunkT - 1;
      const double2* cp2 = reinterpret_cast<const double2*>(
          cur + (long)tn2 * B_SZ * HID_DIM + aOff);
      ca0 = cp2[0]; cb0 = cp2[1];
      const double2* cp3 = reinterpret_cast<const double2*>(
          cur + (long)tn3 * B_SZ * HID_DIM + aOff);
      ca1 = cp3[0]; cb1 = cp3[1];

      float4 sp0, sp1;
      float* sp0v = &sp0.x; float* sp1v = &sp1.x;
      const float* s1v = &s1.x;
#pragma unroll
      for (int j = 0; j < 4; ++j) {
        double m = 0.9 * m1[j];
        m = m + cu0[j];
        m = m - (double)s1v[j];
        sp0v[j] = (m > 1.0) ? 1.0f : 0.0f;
        m1[j] = m;
      }
      if (two) {
#pragma unroll
        for (int j = 0; j < 4; ++j) {
          double m = 0.9 * m1[j];
          m = m + cu1[j];
          m = m - (double)sp0v[j];
          sp1v[j] = (m > 1.0) ? 1.0f : 0.0f;
          m1[j] = m;
        }
        s1 = sp1;
      } else {
        s1 = sp0;
      }
      *reinterpret_cast<float4*>(&spkl[0][sl * HID_DIM + q4]) = sp0;
      if (two)
        *reinterpret_cast<float4*>(&spkl[1][sl * HID_DIM + q4]) = sp1;
    }
    __syncthreads();
    if (pb) {
      const float* wr = &w2l[oo * HID_DIM] + hf * 50;
#pragma unroll 1
      for (int u = 0; u < 2; ++u) {
        if (u == 1 && !two) break;
        const float* sr = &spkl[u][ss * HID_DIM] + hf * 50;
        double a0 = 0.0, a1 = 0.0;
#pragma unroll
        for (int h = 0; h < 50; h += 2) {      // order-free in fp64
          a0 = fma((double)sr[h],     (double)wr[h],     a0);
          a1 = fma((double)sr[h + 1], (double)wr[h + 1], a1);
        }
        double a = a0 + a1;
        a = a + __shfl_xor(a, 1);              // combine halves
        if (hf == 0) {
          double m = 0.9 * m2;
          m = m + a;
          m = m - (double)s2;
          const float sp = (m > 1.0) ? 1.0f : 0.0f;
          m2 = m; s2 = sp; oacc += sp;
        }
      }
    }
    __syncthreads();
  }

  if (pa) {
    double2* mp = reinterpret_cast<double2*>(mem1s + aOff);
    mp[0] = make_double2(m1[0], m1[1]);
    mp[1] = make_double2(m1[2], m1[3]);
    *reinterpret_cast<float4*>(spk1s + aOff) = s1;
  }
  if (pb && hf == 0) {
    mem2s[bOff] = m2; spk2s[bOff] = s2; outs[bOff] = oacc;
    if (isLast) dout[bOff] = oacc;
  }
}

// ---------------- host ----------------
extern "C" void kernel_launch(void* const* d_in, const int* in_sizes, int n_in,
                              void* d_out, int out_size, void* d_ws, size_t ws_size,
                              hipStream_t stream) {
  const float* x  = (const float*)d_in[0];   // [100,2048,784]
  const float* w1 = (const float*)d_in[1];   // [100,784]
  const float* w2 = (const float*)d_in[2];   // [10,100]
  float* out = (float*)d_out;

  char* ws = (char*)d_ws;
  // byte offsets: mem1(d) 1,638,400 | spk1(f) 819,200 | mem2(d) 163,840 |
  //               spk2(f) 81,920 | outacc(f) 81,920 | cur(d, stride 100)...
  double* mem1s = (double*)(ws);
  float*  spk1s = (float*) (ws + 1638400);
  double* mem2s = (double*)(ws + 2457600);
  float*  spk2s = (float*) (ws + 2621440);
  float*  outs  = (float*) (ws + 2703360);
  double* cur   = (double*)(ws + 2785280);

  const size_t perT = (size_t)B_SZ * HID_DIM * 8;  // 1,638,400 B of cur per timestep
  size_t curCap = ws_size > (size_t)2785280 ? ws_size - 2785280 : 0;
  int Tc = (int)(curCap / perT);
  if (Tc > T_STEPS) Tc = T_STEPS;
  if (Tc < 1) Tc = 1;

  for (int t0 = 0; t0 < T_STEPS; t0 += Tc) {
    const int ct = (T_STEPS - t0 < Tc) ? (T_STEPS - t0) : Tc;
    snn_gemm1<<<dim3(ct * (B_SZ / BMR)), dim3(256), 0, stream>>>(
        x + (size_t)t0 * B_SZ * IN_DIM, w1, cur);
    snn_recur<<<dim3(B_SZ / 4), dim3(256), 0, stream>>>(
        cur, w2, mem1s, spk1s, mem2s, spk2s, outs, out,
        ct, (t0 == 0) ? 1 : 0, (t0 + ct >= T_STEPS) ? 1 : 0);
  }
}